// Round 7
// baseline (15185.057 us; speedup 1.0000x reference)
//
#include <hip/hip_runtime.h>
#include <hip/hip_fp16.h>

#define B_ 256
#define S_ 128
#define D_ 2
#define H_ 512
#define NBLK 256

struct alignas(16) H8 { __half2 h[4]; };

__device__ __forceinline__ float sigm(float x){ return 1.f/(1.f+__expf(-x)); }
__device__ __forceinline__ float tanh_(float x){ return 1.f - 2.f/(__expf(2.f*x)+1.f); }

// Agent-scope relaxed accesses (LLC coherence point, no cache flushes).
__device__ __forceinline__ float ldc(const float* p){
    return __hip_atomic_load(p, __ATOMIC_RELAXED, __HIP_MEMORY_SCOPE_AGENT);
}
__device__ __forceinline__ void stc(float* p, float v){
    __hip_atomic_store(p, v, __ATOMIC_RELAXED, __HIP_MEMORY_SCOPE_AGENT);
}
__device__ __forceinline__ unsigned ldu(const unsigned* p){
    return __hip_atomic_load(p, __ATOMIC_RELAXED, __HIP_MEMORY_SCOPE_AGENT);
}
__device__ __forceinline__ void stu(unsigned* p, unsigned v){
    __hip_atomic_store(p, v, __ATOMIC_RELAXED, __HIP_MEMORY_SCOPE_AGENT);
}

// Hierarchical flush-free grid barrier: 16 groups of 16 blocks.
__device__ __forceinline__ void gbar(unsigned* bar){
    __syncthreads();
    if (threadIdx.x == 0) {
        asm volatile("s_waitcnt vmcnt(0)" ::: "memory");
        const int grp = blockIdx.x >> 4;
        unsigned* gc = bar + grp * 16;
        unsigned* gg = bar + 256 + grp * 16;
        unsigned* rc = bar + 512;
        unsigned* rg = bar + 528;
        unsigned gen = ldu(gg);
        if (__hip_atomic_fetch_add(gc, 1u, __ATOMIC_RELAXED, __HIP_MEMORY_SCOPE_AGENT) == 15u) {
            stu(gc, 0u);
            unsigned rgen = ldu(rg);
            if (__hip_atomic_fetch_add(rc, 1u, __ATOMIC_RELAXED, __HIP_MEMORY_SCOPE_AGENT) == 15u) {
                stu(rc, 0u);
                stu(rg, rgen + 1u);
            } else {
                while (ldu(rg) == rgen) __builtin_amdgcn_s_sleep(1);
            }
            stu(gg, gen + 1u);
        } else {
            while (ldu(gg) == gen) __builtin_amdgcn_s_sleep(1);
        }
    }
    __syncthreads();
}

// Batched UC stage: 32 rows into regs first (one latency exposure), then LDS.
__device__ __forceinline__ void stage32(float (*Hs)[H_], const float* src,
                                        size_t str, int b0, int tid){
    float r[32];
#pragma unroll
    for (int i = 0; i < 32; i++) r[i] = ldc(src + (size_t)(b0 + i) * str + tid);
#pragma unroll
    for (int i = 0; i < 32; i++) Hs[i][tid] = r[i];
}
// 16-row variant (dec_p: keeps register pressure down).
__device__ __forceinline__ void stage16(float (*Hs)[H_], const float* src,
                                        size_t str, int b0, int tid){
    float r[16];
#pragma unroll
    for (int i = 0; i < 16; i++) r[i] = ldc(src + (size_t)(b0 + i) * str + tid);
#pragma unroll
    for (int i = 0; i < 16; i++) Hs[i][tid] = r[i];
}

// ---------------------------------------------------------------------------
__global__ __launch_bounds__(256) void prep6(
    const float* __restrict__ dWih, const float* __restrict__ dbih,
    const float* __restrict__ dbhh, const float* __restrict__ ebih,
    const float* __restrict__ ebhh, float* __restrict__ dxw,
    float* __restrict__ ebias)
{
    int j = blockIdx.x * 256 + threadIdx.x;
    const float* row = dWih + (size_t)j * H_;
    float s = 0.f;
    for (int k = 0; k < H_; k++) s += row[k];
    dxw[j]   = dbih[j] + dbhh[j] - s;
    ebias[j] = ebih[j] + ebhh[j];
}

__global__ __launch_bounds__(256) void pack_whh(
    const float* __restrict__ eW, const float* __restrict__ dW,
    float* __restrict__ pe, float* __restrict__ pd)
{
    size_t n = (size_t)blockIdx.x * 256 + threadIdx.x;
    int sel = (int)(n >> 20);
    int m = (int)(n & 1048575);
    int c = m & 3, rw = (m >> 2) & 63, i4 = (m >> 8) & 15;
    int ks = (m >> 12) & 7, jt = m >> 15;
    int g = rw >> 4, hu = rw & 15;
    size_t src = (size_t)(g * H_ + jt * 16 + hu) * H_ + ks * 64 + i4 * 4 + c;
    if (sel) pd[m] = dW[src]; else pe[m] = eW[src];
}

__device__ __forceinline__ void load_w64(const float* Wsrc, int packed,
                                         int jt, int ks, int rw, float* w)
{
    if (packed) {
        const float4* wp = (const float4*)Wsrc + (size_t)(jt * 8 + ks) * 1024 + rw;
#pragma unroll
        for (int i = 0; i < 16; i++) {
            float4 t4 = wp[(size_t)i * 64];
            w[4*i]=t4.x; w[4*i+1]=t4.y; w[4*i+2]=t4.z; w[4*i+3]=t4.w;
        }
    } else {
        int g = rw >> 4, hu = rw & 15;
        const float4* wp = (const float4*)(Wsrc + (size_t)(g * H_ + jt*16 + hu) * H_ + ks * 64);
#pragma unroll
        for (int i = 0; i < 16; i++) {
            float4 t4 = wp[i];
            w[4*i]=t4.x; w[4*i+1]=t4.y; w[4*i+2]=t4.z; w[4*i+3]=t4.w;
        }
    }
}

// ---------------------------------------------------------------------------
// Persistent encoder (unchanged structure from round 6).
// ---------------------------------------------------------------------------
__global__ __launch_bounds__(512, 1) void enc_p(
    const float* __restrict__ x, const float* __restrict__ eWih,
    const float* __restrict__ Wsrc, int packed,
    const float* __restrict__ ebias, float* __restrict__ enc_hs,
    __half* __restrict__ eh16, float* __restrict__ c_fin, unsigned* bar)
{
    __shared__ float smem[16384];
    float (*Hs)[H_]    = (float (*)[H_])smem;
    float (*P)[32][64] = (float (*)[32][64])smem;

    const int tid = threadIdx.x;
    const int ks = tid >> 6, rw = tid & 63;
    const int bt = blockIdx.x >> 5, jt = blockIdx.x & 31;
    const int b0 = bt * 32, hu0 = jt * 16;

    float w[64];
    load_w64(Wsrc, packed, jt, ks, rw, w);

    const int fb = tid >> 4, fh = tid & 15;
    const int fhu = hu0 + fh;
    float eb4[4], wi0[4], wi1[4];
#pragma unroll
    for (int g = 0; g < 4; g++) {
        eb4[g] = ebias[g*H_ + fhu];
        wi0[g] = eWih[(size_t)(g*H_ + fhu)*D_ + 0];
        wi1[g] = eWih[(size_t)(g*H_ + fhu)*D_ + 1];
    }
    float creg = 0.f;

    for (int t = 0; t < S_; t++) {
        float acc[32];
        if (t == 0) {
#pragma unroll
            for (int b = 0; b < 32; b++) acc[b] = 0.f;
        } else {
            stage32(Hs, enc_hs + (size_t)(t - 1) * H_, (size_t)S_ * H_, b0, tid);
            __syncthreads();
#pragma unroll 2
            for (int b = 0; b < 32; b++) {
                const float4* hp = (const float4*)&Hs[b][ks * 64];   // wave-uniform
                float s = 0.f;
#pragma unroll
                for (int i = 0; i < 16; i++) {
                    float4 h4 = hp[i];
                    s += h4.x*w[4*i] + h4.y*w[4*i+1] + h4.z*w[4*i+2] + h4.w*w[4*i+3];
                }
                acc[b] = s;
            }
            __syncthreads();
        }
#pragma unroll
        for (int b = 0; b < 32; b++) P[ks][b][rw ^ ((b & 3) << 4)] = acc[b];
        __syncthreads();
        {
            float z[4];
#pragma unroll
            for (int g = 0; g < 4; g++) {
                int row = g*16 + fh;
                float s2 = 0.f;
#pragma unroll
                for (int k8 = 0; k8 < 8; k8++)
                    s2 += P[k8][fb][row ^ ((fb & 3) << 4)];
                z[g] = s2 + eb4[g];
            }
            int bb = b0 + fb;
            float x0 = x[((size_t)bb*S_ + t)*D_ + 0];
            float x1 = x[((size_t)bb*S_ + t)*D_ + 1];
#pragma unroll
            for (int g = 0; g < 4; g++) z[g] += x0*wi0[g] + x1*wi1[g];
            float cn = sigm(z[1])*creg + sigm(z[0])*tanh_(z[2]);
            float hn = sigm(z[3])*tanh_(cn);
            creg = cn;
            stc(&enc_hs[((size_t)bb*S_ + t)*H_ + fhu], hn);
            if (eh16) eh16[((size_t)bb*S_ + t)*H_ + fhu] = __float2half(hn);
        }
        if (t < S_ - 1) gbar(bar);
    }
    stc(&c_fin[(size_t)(b0 + fb)*H_ + fhu], creg);
}

// ---------------------------------------------------------------------------
// fp32 GEMM, templated output type (half for W1e16).
// ---------------------------------------------------------------------------
template<int BM, int BN, int TM, int TN, typename OT>
__global__ __launch_bounds__((BM/TM)*(BN/TN)) void gemm_bias(
    const float* __restrict__ A, const float* __restrict__ Bm,
    const float* __restrict__ bias, OT* __restrict__ C,
    int M, int N, int K)
{
    constexpr int BK = 32;
    constexpr int TH = (BM / TM) * (BN / TN);
    constexpr int AL = BM * BK / TH;
    constexpr int BL = BN * BK / TH;
    constexpr int RP = TH / BK;
    __shared__ float As[BK][BM + 4];
    __shared__ float Bs[BK][BN + 4];
    const int tid = threadIdx.x;
    const int tn = tid % (BN / TN);
    const int tm = tid / (BN / TN);
    const int m0 = blockIdx.x * BM, n0 = blockIdx.y * BN;
    const int lk = tid % BK, lr = tid / BK;

    float acc[TM][TN];
#pragma unroll
    for (int i = 0; i < TM; i++)
#pragma unroll
        for (int j = 0; j < TN; j++) acc[i][j] = 0.f;

    float areg[AL], breg[BL];
#pragma unroll
    for (int i = 0; i < AL; i++) areg[i] = A[(size_t)(m0 + lr + i * RP) * K + lk];
#pragma unroll
    for (int i = 0; i < BL; i++) breg[i] = Bm[(size_t)(n0 + lr + i * RP) * K + lk];

    const int NC = K / BK;
    for (int c = 0; c < NC; c++) {
        __syncthreads();
#pragma unroll
        for (int i = 0; i < AL; i++) As[lk][lr + i * RP] = areg[i];
#pragma unroll
        for (int i = 0; i < BL; i++) Bs[lk][lr + i * RP] = breg[i];
        __syncthreads();
        if (c + 1 < NC) {
            int k0 = (c + 1) * BK;
#pragma unroll
            for (int i = 0; i < AL; i++) areg[i] = A[(size_t)(m0 + lr + i * RP) * K + k0 + lk];
#pragma unroll
            for (int i = 0; i < BL; i++) breg[i] = Bm[(size_t)(n0 + lr + i * RP) * K + k0 + lk];
        }
#pragma unroll
        for (int k = 0; k < BK; k++) {
            float av[TM], bvv[TN];
#pragma unroll
            for (int i = 0; i < TM; i++) av[i] = As[k][tm * TM + i];
#pragma unroll
            for (int j = 0; j < TN; j++) bvv[j] = Bs[k][tn * TN + j];
#pragma unroll
            for (int i = 0; i < TM; i++)
#pragma unroll
                for (int j = 0; j < TN; j++) acc[i][j] += av[i] * bvv[j];
        }
    }
#pragma unroll
    for (int i = 0; i < TM; i++) {
        int m = m0 + tm * TM + i;
#pragma unroll
        for (int j = 0; j < TN; j++) {
            int n = n0 + tn * TN + j;
            C[(size_t)m * N + n] = (OT)(acc[i][j] + bias[n]);
        }
    }
}

// ---------------------------------------------------------------------------
// Persistent decoder. W1e panel (16 s-rows x 8 k-cols/thread) VGPR-resident
// for the whole kernel -> u-pass is pure register VALU. Phases L and W split
// into two 16-batch halves to keep VGPRs < 256 (8 waves/CU preserved).
// ---------------------------------------------------------------------------
__global__ __launch_bounds__(512, 1) void dec_p(
    const float* __restrict__ Wsrc, int packed,
    const float* __restrict__ dxw,
    const float* __restrict__ W2, const float* __restrict__ b2,
    const float* __restrict__ vv, const float* __restrict__ bv,
    const float* __restrict__ enc_hs, const __half* __restrict__ W1e16,
    const __half* __restrict__ eb16, const float* __restrict__ c_fin,
    float* __restrict__ h_dec, float* __restrict__ w2h,
    float* __restrict__ h_glim, float* __restrict__ out,
    unsigned* bar)
{
    __shared__ float smem[16384];
    float (*HsA)[H_]    = (float (*)[H_])smem;               // [16][512] region A
    float (*P0)[16][64] = (float (*)[16][64])(smem + 8192);  // region B
    float (*P1)[16][64] = (float (*)[16][64])smem;           // overlays A
    float (*Q0)[32][16] = (float (*)[32][16])(smem + 8192);  // [16][32][16]
    float (*Q1)[32][16] = (float (*)[32][16])smem;
    float* qq  = smem;
    float* ua  = smem + 512;
    float* red = smem + 640;
    float* P3  = smem + 1024;     // [8][64][9]

    const int tid = threadIdx.x;
    const int ks = tid >> 6, rw = tid & 63;
    const int bt = blockIdx.x >> 5, jt = blockIdx.x & 31;
    const int b0 = bt * 32, hu0 = jt * 16;
    const int ln = tid & 63, wv = tid >> 6;

    float w[64];
    load_w64(Wsrc, packed, jt, ks, rw, w);

    const int rsub = (tid >> 4) & 3, jj = tid & 15;
    float w2r[16];
    {
        const float4* p4 = (const float4*)(W2 + (size_t)(hu0 + jj)*H_ + ks*64 + rsub*16);
#pragma unroll
        for (int i = 0; i < 4; i++) {
            float4 t4 = p4[i];
            w2r[4*i]=t4.x; w2r[4*i+1]=t4.y; w2r[4*i+2]=t4.z; w2r[4*i+3]=t4.w;
        }
    }

    const int fb = tid >> 4, fh = tid & 15;
    const int fhu = hu0 + fh;
    float db4[4];
#pragma unroll
    for (int g = 0; g < 4; g++) db4[g] = dxw[g*H_ + fhu];
    const float b2f = b2[fhu];
    float creg = c_fin[(size_t)(b0 + fb)*H_ + fhu];

    const int ab = blockIdx.x;
    const __half* w1b = W1e16 + (size_t)ab * S_ * H_;
    const __half* ebh = eb16 ? (eb16 + (size_t)ab * S_ * H_) : (const __half*)nullptr;
    const float* ebf = enc_hs + (size_t)ab * S_ * H_;
    const float4 vr0 = *(const float4*)(vv + ln*8);
    const float4 vr1 = *(const float4*)(vv + ln*8 + 4);
    const float bvr = bv[0];

    // ---- W1e panel -> VGPRs (64 regs): rows wv*16..+16, cols ln*8..+8 ----
    H8 w1r[16];
#pragma unroll
    for (int si = 0; si < 16; si++)
        w1r[si] = *(const H8*)(w1b + (size_t)(wv*16 + si)*H_ + ln*8);

    for (int t = 0; t < S_; t++) {
        // ---------------- phase L: LSTM (two 16-batch halves) ----------------
        {
            const float* hsrc = (t == 0) ? (enc_hs + (size_t)(S_-1)*H_) : h_glim;
            const size_t hstr = (t == 0) ? (size_t)(S_*H_) : (size_t)H_;
            float acc[16];
            stage16(HsA, hsrc, hstr, b0, tid);
            __syncthreads();
#pragma unroll 2
            for (int b = 0; b < 16; b++) {
                const float4* hp = (const float4*)&HsA[b][ks * 64];
                float s = 0.f;
#pragma unroll
                for (int i = 0; i < 16; i++) {
                    float4 h4 = hp[i];
                    s += h4.x*w[4*i] + h4.y*w[4*i+1] + h4.z*w[4*i+2] + h4.w*w[4*i+3];
                }
                acc[b] = s;
            }
            __syncthreads();
#pragma unroll
            for (int b = 0; b < 16; b++) P0[ks][b][rw ^ ((b & 3) << 4)] = acc[b];
            stage16(HsA, hsrc, hstr, b0 + 16, tid);
            __syncthreads();
#pragma unroll 2
            for (int b = 0; b < 16; b++) {
                const float4* hp = (const float4*)&HsA[b][ks * 64];
                float s = 0.f;
#pragma unroll
                for (int i = 0; i < 16; i++) {
                    float4 h4 = hp[i];
                    s += h4.x*w[4*i] + h4.y*w[4*i+1] + h4.z*w[4*i+2] + h4.w*w[4*i+3];
                }
                acc[b] = s;
            }
            __syncthreads();
#pragma unroll
            for (int b = 0; b < 16; b++) P1[ks][b][rw ^ ((b & 3) << 4)] = acc[b];
            __syncthreads();
            if (tid < 256) {
                float (*Pf)[16][64] = (fb < 16) ? P0 : P1;
                const int bl = fb & 15;
                float z[4];
#pragma unroll
                for (int g = 0; g < 4; g++) {
                    int row = g*16 + fh;
                    float s2 = 0.f;
#pragma unroll
                    for (int k8 = 0; k8 < 8; k8++)
                        s2 += Pf[k8][bl][row ^ ((bl & 3) << 4)];
                    z[g] = s2 + db4[g];
                }
                float cn = sigm(z[1])*creg + sigm(z[0])*tanh_(z[2]);
                float hn = sigm(z[3])*tanh_(cn);
                creg = cn;
                stc(&h_dec[(size_t)(b0 + fb)*H_ + fhu], hn);
            }
        }
        gbar(bar);
        // ---------------- phase W: w2h (two 16-batch halves) ----------------
        {
            const int kk = ks * 64 + rsub * 16;
            float a2[16];
            stage16(HsA, h_dec, (size_t)H_, b0, tid);
            __syncthreads();
#pragma unroll 2
            for (int b = 0; b < 16; b++) {
                const float4* hp = (const float4*)&HsA[b][kk];
                float s = 0.f;
#pragma unroll
                for (int i = 0; i < 4; i++) {
                    float4 h4 = hp[i];
                    s += h4.x*w2r[4*i] + h4.y*w2r[4*i+1] + h4.z*w2r[4*i+2] + h4.w*w2r[4*i+3];
                }
                a2[b] = s;
            }
            __syncthreads();
#pragma unroll
            for (int b = 0; b < 16; b++) Q0[b][ks*4 + rsub][jj] = a2[b];
            stage16(HsA, h_dec, (size_t)H_, b0 + 16, tid);
            __syncthreads();
#pragma unroll 2
            for (int b = 0; b < 16; b++) {
                const float4* hp = (const float4*)&HsA[b][kk];
                float s = 0.f;
#pragma unroll
                for (int i = 0; i < 4; i++) {
                    float4 h4 = hp[i];
                    s += h4.x*w2r[4*i] + h4.y*w2r[4*i+1] + h4.z*w2r[4*i+2] + h4.w*w2r[4*i+3];
                }
                a2[b] = s;
            }
            __syncthreads();
#pragma unroll
            for (int b = 0; b < 16; b++) Q1[b][ks*4 + rsub][jj] = a2[b];
            __syncthreads();
            if (tid < 256) {
                float (*Qf)[32][16] = (fb < 16) ? Q0 : Q1;
                const int bl = fb & 15;
                float s2 = 0.f;
#pragma unroll
                for (int p = 0; p < 32; p++) s2 += Qf[bl][p][fh];
                stc(&w2h[(size_t)(b0 + fb)*H_ + fhu], s2 + b2f);
            }
        }
        gbar(bar);
        // ---------------- phase A: attention ----------------
        {
            qq[tid] = ldc(&w2h[(size_t)ab*H_ + tid]);
            __syncthreads();
            float4 q0 = *(float4*)&qq[ln*8];
            float4 q1 = *(float4*)&qq[ln*8 + 4];
#pragma unroll
            for (int si = 0; si < 16; si++) {
                int s = wv*16 + si;
                float2 a0 = __half22float2(w1r[si].h[0]);
                float2 a1 = __half22float2(w1r[si].h[1]);
                float2 a2 = __half22float2(w1r[si].h[2]);
                float2 a3 = __half22float2(w1r[si].h[3]);
                float sum = tanh_(a0.x+q0.x)*vr0.x + tanh_(a0.y+q0.y)*vr0.y
                          + tanh_(a1.x+q0.z)*vr0.z + tanh_(a1.y+q0.w)*vr0.w
                          + tanh_(a2.x+q1.x)*vr1.x + tanh_(a2.y+q1.y)*vr1.y
                          + tanh_(a3.x+q1.z)*vr1.z + tanh_(a3.y+q1.w)*vr1.w;
#pragma unroll
                for (int off = 32; off; off >>= 1) sum += __shfl_xor(sum, off);
                if (ln == 0) ua[s] = sum + bvr;
            }
            __syncthreads();
            float e = 0.f;
            if (tid < 128) {
                float m = ua[tid];
#pragma unroll
                for (int off = 32; off; off >>= 1) m = fmaxf(m, __shfl_xor(m, off));
                if (ln == 0) red[tid >> 6] = m;
            }
            __syncthreads();
            if (tid < 128) {
                float mx = fmaxf(red[0], red[1]);
                e = __expf(ua[tid] - mx);
                float ss = e;
#pragma unroll
                for (int off = 32; off; off >>= 1) ss += __shfl_xor(ss, off);
                if (ln == 0) red[2 + (tid >> 6)] = ss;
            }
            __syncthreads();
            if (tid < 128) {
                float a = e / (red[2] + red[3]);
                ua[tid] = a;
                out[(size_t)ab*S_*S_ + (size_t)t*S_ + tid] = a;
            }
            __syncthreads();
            float acc8[8];
#pragma unroll
            for (int i = 0; i < 8; i++) acc8[i] = 0.f;
            if (ebh) {
#pragma unroll 4
                for (int si = 0; si < 16; si++) {
                    int s = wv*16 + si;
                    H8 e8 = *(const H8*)(ebh + (size_t)s*H_ + ln*8);
                    float a = ua[s];
                    float2 p0 = __half22float2(e8.h[0]);
                    float2 p1 = __half22float2(e8.h[1]);
                    float2 p2 = __half22float2(e8.h[2]);
                    float2 p3 = __half22float2(e8.h[3]);
                    acc8[0] += a*p0.x; acc8[1] += a*p0.y;
                    acc8[2] += a*p1.x; acc8[3] += a*p1.y;
                    acc8[4] += a*p2.x; acc8[5] += a*p2.y;
                    acc8[6] += a*p3.x; acc8[7] += a*p3.y;
                }
            } else {
#pragma unroll 4
                for (int si = 0; si < 16; si++) {
                    int s = wv*16 + si;
                    const float4* ep = (const float4*)(ebf + (size_t)s*H_ + ln*8);
                    float4 e0 = ep[0], e1 = ep[1];
                    float a = ua[s];
                    acc8[0] += a*e0.x; acc8[1] += a*e0.y;
                    acc8[2] += a*e0.z; acc8[3] += a*e0.w;
                    acc8[4] += a*e1.x; acc8[5] += a*e1.y;
                    acc8[6] += a*e1.z; acc8[7] += a*e1.w;
                }
            }
#pragma unroll
            for (int i = 0; i < 8; i++) P3[wv*576 + ln*9 + i] = acc8[i];
            __syncthreads();
            {
                float g = 0.f;
                int base = (tid >> 3) * 9 + (tid & 7);
#pragma unroll
                for (int w8 = 0; w8 < 8; w8++) g += P3[w8*576 + base];
                stc(&h_glim[(size_t)ab*H_ + tid], g);
            }
        }
        if (t < S_ - 1) gbar(bar);
    }
}

// ---------------------------------------------------------------------------
extern "C" void kernel_launch(void* const* d_in, const int* in_sizes, int n_in,
                              void* d_out, int out_size, void* d_ws, size_t ws_size,
                              hipStream_t stream)
{
    const float* x    = (const float*)d_in[0];
    const float* eWih = (const float*)d_in[1];
    const float* eWhh = (const float*)d_in[2];
    const float* ebih = (const float*)d_in[3];
    const float* ebhh = (const float*)d_in[4];
    const float* dWih = (const float*)d_in[5];
    const float* dWhh = (const float*)d_in[6];
    const float* dbih = (const float*)d_in[7];
    const float* dbhh = (const float*)d_in[8];
    const float* W1   = (const float*)d_in[9];
    const float* b1   = (const float*)d_in[10];
    const float* W2   = (const float*)d_in[11];
    const float* b2   = (const float*)d_in[12];
    const float* vv   = (const float*)d_in[13];
    const float* bv   = (const float*)d_in[14];
    float* out = (float*)d_out;

    float* ws      = (float*)d_ws;
    float* enc_hs  = ws;                                   // 16777216
    float* h_dec   = enc_hs + (size_t)B_ * S_ * H_;        // 131072
    float* h_glim  = h_dec  + (size_t)B_ * H_;
    float* w2h     = h_glim + (size_t)B_ * H_;
    float* c_fin   = w2h    + (size_t)B_ * H_;
    float* dxw     = c_fin  + (size_t)B_ * H_;             // 2048
    float* ebias   = dxw    + 2048;                        // 2048
    unsigned* bars = (unsigned*)(ebias + 2048);            // 2048 u32
    __half* W1e16  = (__half*)(ebias + 2048 + 2048);       // 8388608 floats
    float* after16 = (float*)(W1e16) + 8388608;
    __half* eh16   = (__half*)after16;                     // optional, 8388608 f
    float* wpk_e   = after16 + 8388608;                    // optional
    float* wpk_d   = wpk_e + 1048576;

    size_t mand_f   = (size_t)(after16 - ws);              // mandatory floats
    int have_eh16 = (ws_size >= (mand_f + 8388608u) * sizeof(float)) ? 1 : 0;
    int packed    = (ws_size >= (mand_f + 8388608u + 2097152u) * sizeof(float)) ? 1 : 0;
    if (!have_eh16) eh16 = nullptr;

    hipMemsetAsync(bars, 0, 2048 * sizeof(unsigned), stream);
    prep6<<<8, 256, 0, stream>>>(dWih, dbih, dbhh, ebih, ebhh, dxw, ebias);
    if (packed)
        pack_whh<<<8192, 256, 0, stream>>>(eWhh, dWhh, wpk_e, wpk_d);

    const float* We = packed ? wpk_e : eWhh;
    const float* Wd = packed ? wpk_d : dWhh;

    enc_p<<<NBLK, 512, 0, stream>>>(x, eWih, We, packed, ebias, enc_hs, eh16, c_fin, bars);

    gemm_bias<128, 128, 8, 8, __half>
        <<<dim3((B_ * S_) / 128, H_ / 128), 256, 0, stream>>>(
        enc_hs, W1, b1, W1e16, B_ * S_, H_, H_);

    dec_p<<<NBLK, 512, 0, stream>>>(Wd, packed, dxw, W2, b2, vv, bv,
                                    enc_hs, W1e16, eh16, c_fin,
                                    h_dec, w2h, h_glim, out, bars + 1024);
}

// Round 8
// 13776.076 us; speedup vs baseline: 1.1023x; 1.1023x over previous
//
#include <hip/hip_runtime.h>
#include <hip/hip_fp16.h>

#define B_ 256
#define S_ 128
#define D_ 2
#define H_ 512
#define NBLK 256
#define GRP 32     // blocks per independent group (= batches per group)

struct alignas(16) H8 { __half2 h[4]; };

__device__ __forceinline__ float sigm(float x){ return 1.f/(1.f+__expf(-x)); }
__device__ __forceinline__ float tanh_(float x){ return 1.f - 2.f/(__expf(2.f*x)+1.f); }

// Agent-scope relaxed accesses (complete at LLC, bypass non-coherent L2).
__device__ __forceinline__ float ldc(const float* p){
    return __hip_atomic_load(p, __ATOMIC_RELAXED, __HIP_MEMORY_SCOPE_AGENT);
}
__device__ __forceinline__ void stc(float* p, float v){
    __hip_atomic_store(p, v, __ATOMIC_RELAXED, __HIP_MEMORY_SCOPE_AGENT);
}
__device__ __forceinline__ unsigned ldu(const unsigned* p){
    return __hip_atomic_load(p, __ATOMIC_RELAXED, __HIP_MEMORY_SCOPE_AGENT);
}
__device__ __forceinline__ void stu(unsigned* p, unsigned v){
    __hip_atomic_store(p, v, __ATOMIC_RELAXED, __HIP_MEMORY_SCOPE_AGENT);
}

// Group-local (32-block) flush-free barrier. vmcnt drain between the
// count-reset and the generation bump prevents the stale-count race.
__device__ __forceinline__ void gbar32(unsigned* base, int grp){
    __syncthreads();
    if (threadIdx.x == 0) {
        unsigned* c = base + grp * 32;
        unsigned* g = base + grp * 32 + 16;
        asm volatile("s_waitcnt vmcnt(0)" ::: "memory");
        unsigned gen = ldu(g);
        if (__hip_atomic_fetch_add(c, 1u, __ATOMIC_RELAXED, __HIP_MEMORY_SCOPE_AGENT) == GRP - 1u) {
            stu(c, 0u);
            asm volatile("s_waitcnt vmcnt(0)" ::: "memory");
            stu(g, gen + 1u);
        } else {
            while (ldu(g) == gen) __builtin_amdgcn_s_sleep(1);
        }
    }
    __syncthreads();
}

// ---------------------------------------------------------------------------
__global__ __launch_bounds__(256) void prep6(
    const float* __restrict__ dWih, const float* __restrict__ dbih,
    const float* __restrict__ dbhh, const float* __restrict__ ebih,
    const float* __restrict__ ebhh, float* __restrict__ dxw,
    float* __restrict__ ebias)
{
    int j = blockIdx.x * 256 + threadIdx.x;
    const float* row = dWih + (size_t)j * H_;
    float s = 0.f;
    for (int k = 0; k < H_; k++) s += row[k];
    dxw[j]   = dbih[j] + dbhh[j] - s;
    ebias[j] = ebih[j] + ebhh[j];
}

__global__ __launch_bounds__(256) void pack_whh(
    const float* __restrict__ eW, const float* __restrict__ dW,
    float* __restrict__ pe, float* __restrict__ pd)
{
    size_t n = (size_t)blockIdx.x * 256 + threadIdx.x;
    int sel = (int)(n >> 20);
    int m = (int)(n & 1048575);
    int c = m & 3, rw = (m >> 2) & 63, i4 = (m >> 8) & 15;
    int ks = (m >> 12) & 7, jt = m >> 15;
    int g = rw >> 4, hu = rw & 15;
    size_t src = (size_t)(g * H_ + jt * 16 + hu) * H_ + ks * 64 + i4 * 4 + c;
    if (sel) pd[m] = dW[src]; else pe[m] = eW[src];
}

__device__ __forceinline__ void load_w64(const float* Wsrc, int packed,
                                         int jt, int ks, int rw, float* w)
{
    if (packed) {
        const float4* wp = (const float4*)Wsrc + (size_t)(jt * 8 + ks) * 1024 + rw;
#pragma unroll
        for (int i = 0; i < 16; i++) {
            float4 t4 = wp[(size_t)i * 64];
            w[4*i]=t4.x; w[4*i+1]=t4.y; w[4*i+2]=t4.z; w[4*i+3]=t4.w;
        }
    } else {
        int g = rw >> 4, hu = rw & 15;
        const float4* wp = (const float4*)(Wsrc + (size_t)(g * H_ + jt*16 + hu) * H_ + ks * 64);
#pragma unroll
        for (int i = 0; i < 16; i++) {
            float4 t4 = wp[i];
            w[4*i]=t4.x; w[4*i+1]=t4.y; w[4*i+2]=t4.z; w[4*i+3]=t4.w;
        }
    }
}

// ---------------------------------------------------------------------------
// Persistent encoder, GROUP-LOCAL barriers: 8 groups x 32 blocks; group g
// owns batches 32g..32g+31; block (g,jt) holds weight rows jt*16 slice.
// ---------------------------------------------------------------------------
__global__ __launch_bounds__(512, 1) void enc_p(
    const float* __restrict__ x, const float* __restrict__ eWih,
    const float* __restrict__ Wsrc, int packed,
    const float* __restrict__ ebias, float* __restrict__ enc_hs,
    __half* __restrict__ eh16, float* __restrict__ c_fin, unsigned* bar)
{
    __shared__ float work[8192];                       // 32KB
    float (*Hs)[H_]    = (float (*)[H_])work;          // [16][512]
    float (*P)[16][64] = (float (*)[16][64])work;      // overlay

    const int tid = threadIdx.x;
    const int ks = tid >> 6, rw = tid & 63;
    const int grp = blockIdx.x >> 5, jt = blockIdx.x & 31;
    const int b0 = grp * GRP, hu0 = jt * 16;

    float w[64];
    load_w64(Wsrc, packed, jt, ks, rw, w);

    const int fb = tid >> 4, fh = tid & 15;            // finalize roles
    const int fhu = hu0 + fh;
    float eb4[4], wi0[4], wi1[4];
#pragma unroll
    for (int g = 0; g < 4; g++) {
        eb4[g] = ebias[g*H_ + fhu];
        wi0[g] = eWih[(size_t)(g*H_ + fhu)*D_ + 0];
        wi1[g] = eWih[(size_t)(g*H_ + fhu)*D_ + 1];
    }
    float creg0 = 0.f, creg1 = 0.f;

    for (int t = 0; t < S_; t++) {
#pragma unroll 1
        for (int hf = 0; hf < 2; hf++) {
            float acc[16];
            if (t == 0) {
#pragma unroll
                for (int b = 0; b < 16; b++) acc[b] = 0.f;
            } else {
                {
                    float r[16];
                    const float* src = enc_hs + (size_t)(t - 1) * H_;
#pragma unroll
                    for (int i = 0; i < 16; i++)
                        r[i] = ldc(src + (size_t)(b0 + hf*16 + i) * (S_*H_) + tid);
#pragma unroll
                    for (int i = 0; i < 16; i++) Hs[i][tid] = r[i];
                }
                __syncthreads();
#pragma unroll 2
                for (int b = 0; b < 16; b++) {
                    const float4* hp = (const float4*)&Hs[b][ks * 64];  // wave-uniform
                    float s = 0.f;
#pragma unroll
                    for (int i = 0; i < 16; i++) {
                        float4 h4 = hp[i];
                        s += h4.x*w[4*i] + h4.y*w[4*i+1] + h4.z*w[4*i+2] + h4.w*w[4*i+3];
                    }
                    acc[b] = s;
                }
                __syncthreads();
            }
#pragma unroll
            for (int b = 0; b < 16; b++) P[ks][b][rw ^ ((b & 3) << 4)] = acc[b];
            __syncthreads();
            if (tid < 256) {
                float z[4];
#pragma unroll
                for (int g = 0; g < 4; g++) {
                    int row = g*16 + fh;
                    float s2 = 0.f;
#pragma unroll
                    for (int k8 = 0; k8 < 8; k8++)
                        s2 += P[k8][fb][row ^ ((fb & 3) << 4)];
                    z[g] = s2 + eb4[g];
                }
                int bb = b0 + hf*16 + fb;
                float x0 = x[((size_t)bb*S_ + t)*D_ + 0];
                float x1 = x[((size_t)bb*S_ + t)*D_ + 1];
#pragma unroll
                for (int g = 0; g < 4; g++) z[g] += x0*wi0[g] + x1*wi1[g];
                float cold = hf ? creg1 : creg0;
                float cn = sigm(z[1])*cold + sigm(z[0])*tanh_(z[2]);
                float hn = sigm(z[3])*tanh_(cn);
                if (hf) creg1 = cn; else creg0 = cn;
                stc(&enc_hs[((size_t)bb*S_ + t)*H_ + fhu], hn);
                if (eh16) eh16[((size_t)bb*S_ + t)*H_ + fhu] = __float2half(hn);
            }
            __syncthreads();
        }
        if (t < S_ - 1) gbar32(bar, grp);
    }
    if (tid < 256) {
        stc(&c_fin[(size_t)(b0 + fb)*H_ + fhu],      creg0);
        stc(&c_fin[(size_t)(b0 + 16 + fb)*H_ + fhu], creg1);
    }
}

// ---------------------------------------------------------------------------
// fp32 GEMM, fp16 output (W1e16).
// ---------------------------------------------------------------------------
template<int BM, int BN, int TM, int TN, typename OT>
__global__ __launch_bounds__((BM/TM)*(BN/TN)) void gemm_bias(
    const float* __restrict__ A, const float* __restrict__ Bm,
    const float* __restrict__ bias, OT* __restrict__ C,
    int M, int N, int K)
{
    constexpr int BK = 32;
    constexpr int TH = (BM / TM) * (BN / TN);
    constexpr int AL = BM * BK / TH;
    constexpr int BL = BN * BK / TH;
    constexpr int RP = TH / BK;
    __shared__ float As[BK][BM + 4];
    __shared__ float Bs[BK][BN + 4];
    const int tid = threadIdx.x;
    const int tn = tid % (BN / TN);
    const int tm = tid / (BN / TN);
    const int m0 = blockIdx.x * BM, n0 = blockIdx.y * BN;
    const int lk = tid % BK, lr = tid / BK;

    float acc[TM][TN];
#pragma unroll
    for (int i = 0; i < TM; i++)
#pragma unroll
        for (int j = 0; j < TN; j++) acc[i][j] = 0.f;

    float areg[AL], breg[BL];
#pragma unroll
    for (int i = 0; i < AL; i++) areg[i] = A[(size_t)(m0 + lr + i * RP) * K + lk];
#pragma unroll
    for (int i = 0; i < BL; i++) breg[i] = Bm[(size_t)(n0 + lr + i * RP) * K + lk];

    const int NC = K / BK;
    for (int c = 0; c < NC; c++) {
        __syncthreads();
#pragma unroll
        for (int i = 0; i < AL; i++) As[lk][lr + i * RP] = areg[i];
#pragma unroll
        for (int i = 0; i < BL; i++) Bs[lk][lr + i * RP] = breg[i];
        __syncthreads();
        if (c + 1 < NC) {
            int k0 = (c + 1) * BK;
#pragma unroll
            for (int i = 0; i < AL; i++) areg[i] = A[(size_t)(m0 + lr + i * RP) * K + k0 + lk];
#pragma unroll
            for (int i = 0; i < BL; i++) breg[i] = Bm[(size_t)(n0 + lr + i * RP) * K + k0 + lk];
        }
#pragma unroll
        for (int k = 0; k < BK; k++) {
            float av[TM], bvv[TN];
#pragma unroll
            for (int i = 0; i < TM; i++) av[i] = As[k][tm * TM + i];
#pragma unroll
            for (int j = 0; j < TN; j++) bvv[j] = Bs[k][tn * TN + j];
#pragma unroll
            for (int i = 0; i < TM; i++)
#pragma unroll
                for (int j = 0; j < TN; j++) acc[i][j] += av[i] * bvv[j];
        }
    }
#pragma unroll
    for (int i = 0; i < TM; i++) {
        int m = m0 + tm * TM + i;
#pragma unroll
        for (int j = 0; j < TN; j++) {
            int n = n0 + tn * TN + j;
            C[(size_t)m * N + n] = (OT)(acc[i][j] + bias[n]);
        }
    }
}

// ---------------------------------------------------------------------------
// Persistent decoder, GROUP-LOCAL barriers. Block ab handles attention for
// batch ab with its W1e panel PINNED IN LDS (128KB fp16); LSTM/W2h sliced
// across the 32 blocks of group ab>>5. LDS = 128KB pin + 32KB work = 160KB.
// ---------------------------------------------------------------------------
__global__ __launch_bounds__(512, 1) void dec_p(
    const float* __restrict__ Wsrc, int packed,
    const float* __restrict__ dxw,
    const float* __restrict__ W2, const float* __restrict__ b2,
    const float* __restrict__ vv, const float* __restrict__ bv,
    const float* __restrict__ enc_hs, const __half* __restrict__ W1e16,
    const __half* __restrict__ eb16, const float* __restrict__ c_fin,
    float* __restrict__ h_dec, float* __restrict__ w2h,
    float* __restrict__ h_glim, float* __restrict__ out,
    unsigned* bar)
{
    extern __shared__ char smem_raw[];
    __half* w1l = (__half*)smem_raw;                   // [128][512] fp16, 128KB
    float* work = (float*)(smem_raw + 131072);         // 8192 floats, 32KB
    float (*Hs)[H_]     = (float (*)[H_])work;
    float (*P)[16][64]  = (float (*)[16][64])work;
    float (*Q)[32][16]  = (float (*)[32][16])work;
    float* qq  = work;
    float* ua  = work + 512;
    float* red = work + 640;
    float* P3  = work + 1024;                          // [8][64][9]

    const int tid = threadIdx.x;
    const int ks = tid >> 6, rw = tid & 63;
    const int ab = blockIdx.x;                         // attention batch
    const int grp = ab >> 5, jt = ab & 31;
    const int b0 = grp * GRP, hu0 = jt * 16;
    const int ln = tid & 63, wv = tid >> 6;

    float w[64];
    load_w64(Wsrc, packed, jt, ks, rw, w);

    const int rsub = (tid >> 4) & 3, jj = tid & 15;
    float w2r[16];
    {
        const float4* p4 = (const float4*)(W2 + (size_t)(hu0 + jj)*H_ + ks*64 + rsub*16);
#pragma unroll
        for (int i = 0; i < 4; i++) {
            float4 t4 = p4[i];
            w2r[4*i]=t4.x; w2r[4*i+1]=t4.y; w2r[4*i+2]=t4.z; w2r[4*i+3]=t4.w;
        }
    }

    const int fb = tid >> 4, fh = tid & 15;
    const int fhu = hu0 + fh;
    float db4[4];
#pragma unroll
    for (int g = 0; g < 4; g++) db4[g] = dxw[g*H_ + fhu];
    const float b2f = b2[fhu];
    float creg0 = c_fin[(size_t)(b0 + (fb & 15))*H_ + fhu];
    float creg1 = c_fin[(size_t)(b0 + 16 + (fb & 15))*H_ + fhu];

    const __half* ebh = eb16 ? (eb16 + (size_t)ab * S_ * H_) : (const __half*)nullptr;
    const float* ebf = enc_hs + (size_t)ab * S_ * H_;
    const float4 vr0 = *(const float4*)(vv + ln*8);
    const float4 vr1 = *(const float4*)(vv + ln*8 + 4);
    const float bvr = bv[0];

    // ---- pin this batch's W1e panel in LDS (plain loads; cross-kernel ok) ----
    {
        const H8* src = (const H8*)(W1e16 + (size_t)ab * S_ * H_);
        H8* dst = (H8*)w1l;
#pragma unroll
        for (int i = 0; i < 16; i++) dst[tid + i * 512] = src[tid + i * 512];
    }
    __syncthreads();

    for (int t = 0; t < S_; t++) {
        // ================ phase L: LSTM ================
        {
            const float* hsrc = (t == 0) ? (enc_hs + (size_t)(S_-1)*H_) : h_glim;
            const size_t hstr = (t == 0) ? (size_t)(S_*H_) : (size_t)H_;
#pragma unroll 1
            for (int hf = 0; hf < 2; hf++) {
                {
                    float r[16];
#pragma unroll
                    for (int i = 0; i < 16; i++)
                        r[i] = ldc(hsrc + (size_t)(b0 + hf*16 + i) * hstr + tid);
#pragma unroll
                    for (int i = 0; i < 16; i++) Hs[i][tid] = r[i];
                }
                __syncthreads();
                float acc[16];
#pragma unroll 2
                for (int b = 0; b < 16; b++) {
                    const float4* hp = (const float4*)&Hs[b][ks * 64];
                    float s = 0.f;
#pragma unroll
                    for (int i = 0; i < 16; i++) {
                        float4 h4 = hp[i];
                        s += h4.x*w[4*i] + h4.y*w[4*i+1] + h4.z*w[4*i+2] + h4.w*w[4*i+3];
                    }
                    acc[b] = s;
                }
                __syncthreads();
#pragma unroll
                for (int b = 0; b < 16; b++) P[ks][b][rw ^ ((b & 3) << 4)] = acc[b];
                __syncthreads();
                if (tid < 256) {
                    float z[4];
#pragma unroll
                    for (int g = 0; g < 4; g++) {
                        int row = g*16 + fh;
                        float s2 = 0.f;
#pragma unroll
                        for (int k8 = 0; k8 < 8; k8++)
                            s2 += P[k8][fb][row ^ ((fb & 3) << 4)];
                        z[g] = s2 + db4[g];
                    }
                    float cold = hf ? creg1 : creg0;
                    float cn = sigm(z[1])*cold + sigm(z[0])*tanh_(z[2]);
                    float hn = sigm(z[3])*tanh_(cn);
                    if (hf) creg1 = cn; else creg0 = cn;
                    stc(&h_dec[(size_t)(b0 + hf*16 + fb)*H_ + fhu], hn);
                }
                __syncthreads();
            }
        }
        gbar32(bar, grp);
        // ================ phase W: w2h ================
        {
            const int kk = ks * 64 + rsub * 16;
#pragma unroll 1
            for (int hf = 0; hf < 2; hf++) {
                {
                    float r[16];
#pragma unroll
                    for (int i = 0; i < 16; i++)
                        r[i] = ldc(h_dec + (size_t)(b0 + hf*16 + i) * H_ + tid);
#pragma unroll
                    for (int i = 0; i < 16; i++) Hs[i][tid] = r[i];
                }
                __syncthreads();
                float a2[16];
#pragma unroll 2
                for (int b = 0; b < 16; b++) {
                    const float4* hp = (const float4*)&Hs[b][kk];
                    float s = 0.f;
#pragma unroll
                    for (int i = 0; i < 4; i++) {
                        float4 h4 = hp[i];
                        s += h4.x*w2r[4*i] + h4.y*w2r[4*i+1] + h4.z*w2r[4*i+2] + h4.w*w2r[4*i+3];
                    }
                    a2[b] = s;
                }
                __syncthreads();
#pragma unroll
                for (int b = 0; b < 16; b++) Q[b][ks*4 + rsub][jj] = a2[b];
                __syncthreads();
                if (tid < 256) {
                    float s2 = 0.f;
#pragma unroll
                    for (int p = 0; p < 32; p++) s2 += Q[fb][p][fh];
                    stc(&w2h[(size_t)(b0 + hf*16 + fb)*H_ + fhu], s2 + b2f);
                }
                __syncthreads();
            }
        }
        gbar32(bar, grp);
        // ================ phase A: attention ================
        {
            qq[tid] = ldc(&w2h[(size_t)ab*H_ + tid]);
            // prefetch eh16 rows for the glimpse (independent of u-pass)
            H8 e8[16];
            if (ebh) {
#pragma unroll
                for (int si = 0; si < 16; si++)
                    e8[si] = *(const H8*)(ebh + (size_t)(wv*16 + si)*H_ + ln*8);
            }
            __syncthreads();
            float4 q0 = *(float4*)&qq[ln*8];
            float4 q1 = *(float4*)&qq[ln*8 + 4];
#pragma unroll
            for (int si = 0; si < 16; si++) {
                int s = wv*16 + si;
                H8 w8 = *(const H8*)&w1l[(size_t)s*H_ + ln*8];   // LDS, conflict-free
                float2 a0 = __half22float2(w8.h[0]);
                float2 a1 = __half22float2(w8.h[1]);
                float2 a2 = __half22float2(w8.h[2]);
                float2 a3 = __half22float2(w8.h[3]);
                float sum = tanh_(a0.x+q0.x)*vr0.x + tanh_(a0.y+q0.y)*vr0.y
                          + tanh_(a1.x+q0.z)*vr0.z + tanh_(a1.y+q0.w)*vr0.w
                          + tanh_(a2.x+q1.x)*vr1.x + tanh_(a2.y+q1.y)*vr1.y
                          + tanh_(a3.x+q1.z)*vr1.z + tanh_(a3.y+q1.w)*vr1.w;
#pragma unroll
                for (int off = 32; off; off >>= 1) sum += __shfl_xor(sum, off);
                if (ln == 0) ua[s] = sum + bvr;
            }
            __syncthreads();
            float e = 0.f;
            if (tid < 128) {
                float m = ua[tid];
#pragma unroll
                for (int off = 32; off; off >>= 1) m = fmaxf(m, __shfl_xor(m, off));
                if (ln == 0) red[tid >> 6] = m;
            }
            __syncthreads();
            if (tid < 128) {
                float mx = fmaxf(red[0], red[1]);
                e = __expf(ua[tid] - mx);
                float ss = e;
#pragma unroll
                for (int off = 32; off; off >>= 1) ss += __shfl_xor(ss, off);
                if (ln == 0) red[2 + (tid >> 6)] = ss;
            }
            __syncthreads();
            if (tid < 128) {
                float a = e / (red[2] + red[3]);
                ua[tid] = a;
                out[(size_t)ab*S_*S_ + (size_t)t*S_ + tid] = a;
            }
            __syncthreads();
            float acc8[8];
#pragma unroll
            for (int i = 0; i < 8; i++) acc8[i] = 0.f;
            if (ebh) {
#pragma unroll
                for (int si = 0; si < 16; si++) {
                    int s = wv*16 + si;
                    float a = ua[s];
                    float2 p0 = __half22float2(e8[si].h[0]);
                    float2 p1 = __half22float2(e8[si].h[1]);
                    float2 p2 = __half22float2(e8[si].h[2]);
                    float2 p3 = __half22float2(e8[si].h[3]);
                    acc8[0] += a*p0.x; acc8[1] += a*p0.y;
                    acc8[2] += a*p1.x; acc8[3] += a*p1.y;
                    acc8[4] += a*p2.x; acc8[5] += a*p2.y;
                    acc8[6] += a*p3.x; acc8[7] += a*p3.y;
                }
            } else {
#pragma unroll 4
                for (int si = 0; si < 16; si++) {
                    int s = wv*16 + si;
                    const float4* ep = (const float4*)(ebf + (size_t)s*H_ + ln*8);
                    float4 e0 = ep[0], e1 = ep[1];
                    float a = ua[s];
                    acc8[0] += a*e0.x; acc8[1] += a*e0.y;
                    acc8[2] += a*e0.z; acc8[3] += a*e0.w;
                    acc8[4] += a*e1.x; acc8[5] += a*e1.y;
                    acc8[6] += a*e1.z; acc8[7] += a*e1.w;
                }
            }
#pragma unroll
            for (int i = 0; i < 8; i++) P3[wv*576 + ln*9 + i] = acc8[i];
            __syncthreads();
            {
                float g = 0.f;
                int base = (tid >> 3) * 9 + (tid & 7);
#pragma unroll
                for (int w8 = 0; w8 < 8; w8++) g += P3[w8*576 + base];
                stc(&h_glim[(size_t)ab*H_ + tid], g);
            }
        }
        if (t < S_ - 1) gbar32(bar, grp);
    }
}

// ---------------------------------------------------------------------------
extern "C" void kernel_launch(void* const* d_in, const int* in_sizes, int n_in,
                              void* d_out, int out_size, void* d_ws, size_t ws_size,
                              hipStream_t stream)
{
    const float* x    = (const float*)d_in[0];
    const float* eWih = (const float*)d_in[1];
    const float* eWhh = (const float*)d_in[2];
    const float* ebih = (const float*)d_in[3];
    const float* ebhh = (const float*)d_in[4];
    const float* dWih = (const float*)d_in[5];
    const float* dWhh = (const float*)d_in[6];
    const float* dbih = (const float*)d_in[7];
    const float* dbhh = (const float*)d_in[8];
    const float* W1   = (const float*)d_in[9];
    const float* b1   = (const float*)d_in[10];
    const float* W2   = (const float*)d_in[11];
    const float* b2   = (const float*)d_in[12];
    const float* vv   = (const float*)d_in[13];
    const float* bv   = (const float*)d_in[14];
    float* out = (float*)d_out;

    float* ws      = (float*)d_ws;
    float* enc_hs  = ws;                                   // 16777216
    float* h_dec   = enc_hs + (size_t)B_ * S_ * H_;        // 131072
    float* h_glim  = h_dec  + (size_t)B_ * H_;
    float* w2h     = h_glim + (size_t)B_ * H_;
    float* c_fin   = w2h    + (size_t)B_ * H_;
    float* dxw     = c_fin  + (size_t)B_ * H_;             // 2048
    float* ebias   = dxw    + 2048;                        // 2048
    unsigned* bars = (unsigned*)(ebias + 2048);            // 1024 u32
    __half* W1e16  = (__half*)(ebias + 2048 + 1024);       // 8388608 floats
    float* after16 = (float*)(W1e16) + 8388608;
    __half* eh16   = (__half*)after16;                     // optional, 8388608 f
    float* wpk_e   = after16 + 8388608;                    // optional
    float* wpk_d   = wpk_e + 1048576;

    size_t mand_f   = (size_t)(after16 - ws);
    int have_eh16 = (ws_size >= (mand_f + 8388608u) * sizeof(float)) ? 1 : 0;
    int packed    = (ws_size >= (mand_f + 8388608u + 2097152u) * sizeof(float)) ? 1 : 0;
    if (!have_eh16) eh16 = nullptr;

    hipMemsetAsync(bars, 0, 1024 * sizeof(unsigned), stream);
    prep6<<<8, 256, 0, stream>>>(dWih, dbih, dbhh, ebih, ebhh, dxw, ebias);
    if (packed)
        pack_whh<<<8192, 256, 0, stream>>>(eWhh, dWhh, wpk_e, wpk_d);

    const float* We = packed ? wpk_e : eWhh;
    const float* Wd = packed ? wpk_d : dWhh;

    enc_p<<<NBLK, 512, 0, stream>>>(x, eWih, We, packed, ebias, enc_hs, eh16,
                                    c_fin, bars);

    gemm_bias<128, 128, 8, 8, __half>
        <<<dim3((B_ * S_) / 128, H_ / 128), 256, 0, stream>>>(
        enc_hs, W1, b1, W1e16, B_ * S_, H_, H_);

    dec_p<<<NBLK, 512, 163840, stream>>>(Wd, packed, dxw, W2, b2, vv, bv,
                                         enc_hs, W1e16, eh16, c_fin,
                                         h_dec, w2h, h_glim, out, bars + 512);
}

// Round 9
// 11028.686 us; speedup vs baseline: 1.3769x; 1.2491x over previous
//
#include <hip/hip_runtime.h>
#include <hip/hip_fp16.h>

#define B_ 256
#define S_ 128
#define D_ 2
#define H_ 512
#define NBLK 256
#define GRP 32     // blocks per independent group (= batches per group)

struct alignas(16) H8 { __half2 h[4]; };

__device__ __forceinline__ float sigm(float x){ return 1.f/(1.f+__expf(-x)); }
__device__ __forceinline__ float tanh_(float x){ return 1.f - 2.f/(__expf(2.f*x)+1.f); }

// Agent-scope relaxed accesses (complete at LLC, bypass non-coherent L2).
__device__ __forceinline__ float ldc(const float* p){
    return __hip_atomic_load(p, __ATOMIC_RELAXED, __HIP_MEMORY_SCOPE_AGENT);
}
__device__ __forceinline__ void stc(float* p, float v){
    __hip_atomic_store(p, v, __ATOMIC_RELAXED, __HIP_MEMORY_SCOPE_AGENT);
}
__device__ __forceinline__ unsigned ldu(const unsigned* p){
    return __hip_atomic_load(p, __ATOMIC_RELAXED, __HIP_MEMORY_SCOPE_AGENT);
}
__device__ __forceinline__ void stu(unsigned* p, unsigned v){
    __hip_atomic_store(p, v, __ATOMIC_RELAXED, __HIP_MEMORY_SCOPE_AGENT);
}

// Group-local (32-block) flush-free barrier. vmcnt drain between the
// count-reset and the generation bump prevents the stale-count race.
__device__ __forceinline__ void gbar32(unsigned* base, int grp){
    __syncthreads();
    if (threadIdx.x == 0) {
        unsigned* c = base + grp * 32;
        unsigned* g = base + grp * 32 + 16;
        asm volatile("s_waitcnt vmcnt(0)" ::: "memory");
        unsigned gen = ldu(g);
        if (__hip_atomic_fetch_add(c, 1u, __ATOMIC_RELAXED, __HIP_MEMORY_SCOPE_AGENT) == GRP - 1u) {
            stu(c, 0u);
            asm volatile("s_waitcnt vmcnt(0)" ::: "memory");
            stu(g, gen + 1u);
        } else {
            while (ldu(g) == gen) __builtin_amdgcn_s_sleep(4);
        }
    }
    __syncthreads();
}

// ---------------------------------------------------------------------------
__global__ __launch_bounds__(256) void prep6(
    const float* __restrict__ dWih, const float* __restrict__ dbih,
    const float* __restrict__ dbhh, const float* __restrict__ ebih,
    const float* __restrict__ ebhh, float* __restrict__ dxw,
    float* __restrict__ ebias)
{
    int j = blockIdx.x * 256 + threadIdx.x;
    const float* row = dWih + (size_t)j * H_;
    float s = 0.f;
    for (int k = 0; k < H_; k++) s += row[k];
    dxw[j]   = dbih[j] + dbhh[j] - s;
    ebias[j] = ebih[j] + ebhh[j];
}

__global__ __launch_bounds__(256) void pack_whh(
    const float* __restrict__ eW, const float* __restrict__ dW,
    float* __restrict__ pe, float* __restrict__ pd)
{
    size_t n = (size_t)blockIdx.x * 256 + threadIdx.x;
    int sel = (int)(n >> 20);
    int m = (int)(n & 1048575);
    int c = m & 3, rw = (m >> 2) & 63, i4 = (m >> 8) & 15;
    int ks = (m >> 12) & 7, jt = m >> 15;
    int g = rw >> 4, hu = rw & 15;
    size_t src = (size_t)(g * H_ + jt * 16 + hu) * H_ + ks * 64 + i4 * 4 + c;
    if (sel) pd[m] = dW[src]; else pe[m] = eW[src];
}

__device__ __forceinline__ void load_w64(const float* Wsrc, int packed,
                                         int jt, int ks, int rw, float* w)
{
    if (packed) {
        const float4* wp = (const float4*)Wsrc + (size_t)(jt * 8 + ks) * 1024 + rw;
#pragma unroll
        for (int i = 0; i < 16; i++) {
            float4 t4 = wp[(size_t)i * 64];
            w[4*i]=t4.x; w[4*i+1]=t4.y; w[4*i+2]=t4.z; w[4*i+3]=t4.w;
        }
    } else {
        int g = rw >> 4, hu = rw & 15;
        const float4* wp = (const float4*)(Wsrc + (size_t)(g * H_ + jt*16 + hu) * H_ + ks * 64);
#pragma unroll
        for (int i = 0; i < 16; i++) {
            float4 t4 = wp[i];
            w[4*i]=t4.x; w[4*i+1]=t4.y; w[4*i+2]=t4.z; w[4*i+3]=t4.w;
        }
    }
}

// ---------------------------------------------------------------------------
// Persistent encoder, GROUP-LOCAL barriers: 8 groups x 32 blocks; group g
// owns batches 32g..32g+31; block (g,jt) holds weight rows jt*16 slice.
// ---------------------------------------------------------------------------
__global__ __launch_bounds__(512, 1) void enc_p(
    const float* __restrict__ x, const float* __restrict__ eWih,
    const float* __restrict__ Wsrc, int packed,
    const float* __restrict__ ebias, float* __restrict__ enc_hs,
    __half* __restrict__ eh16, float* __restrict__ c_fin, unsigned* bar)
{
    __shared__ float work[8192];                       // 32KB
    float (*Hs)[H_]    = (float (*)[H_])work;          // [16][512]
    float (*P)[16][64] = (float (*)[16][64])work;      // overlay

    const int tid = threadIdx.x;
    const int ks = tid >> 6, rw = tid & 63;
    const int grp = blockIdx.x >> 5, jt = blockIdx.x & 31;
    const int b0 = grp * GRP, hu0 = jt * 16;

    float w[64];
    load_w64(Wsrc, packed, jt, ks, rw, w);

    const int fb = tid >> 4, fh = tid & 15;            // finalize roles
    const int fhu = hu0 + fh;
    float eb4[4], wi0[4], wi1[4];
#pragma unroll
    for (int g = 0; g < 4; g++) {
        eb4[g] = ebias[g*H_ + fhu];
        wi0[g] = eWih[(size_t)(g*H_ + fhu)*D_ + 0];
        wi1[g] = eWih[(size_t)(g*H_ + fhu)*D_ + 1];
    }
    float creg0 = 0.f, creg1 = 0.f;

    for (int t = 0; t < S_; t++) {
#pragma unroll 1
        for (int hf = 0; hf < 2; hf++) {
            float acc[16];
            if (t == 0) {
#pragma unroll
                for (int b = 0; b < 16; b++) acc[b] = 0.f;
            } else {
                {
                    float r[16];
                    const float* src = enc_hs + (size_t)(t - 1) * H_;
#pragma unroll
                    for (int i = 0; i < 16; i++)
                        r[i] = ldc(src + (size_t)(b0 + hf*16 + i) * (S_*H_) + tid);
#pragma unroll
                    for (int i = 0; i < 16; i++) Hs[i][tid] = r[i];
                }
                __syncthreads();
#pragma unroll 2
                for (int b = 0; b < 16; b++) {
                    const float4* hp = (const float4*)&Hs[b][ks * 64];  // wave-uniform
                    float s = 0.f;
#pragma unroll
                    for (int i = 0; i < 16; i++) {
                        float4 h4 = hp[i];
                        s += h4.x*w[4*i] + h4.y*w[4*i+1] + h4.z*w[4*i+2] + h4.w*w[4*i+3];
                    }
                    acc[b] = s;
                }
                __syncthreads();
            }
#pragma unroll
            for (int b = 0; b < 16; b++) P[ks][b][rw ^ ((b & 3) << 4)] = acc[b];
            __syncthreads();
            if (tid < 256) {
                float z[4];
#pragma unroll
                for (int g = 0; g < 4; g++) {
                    int row = g*16 + fh;
                    float s2 = 0.f;
#pragma unroll
                    for (int k8 = 0; k8 < 8; k8++)
                        s2 += P[k8][fb][row ^ ((fb & 3) << 4)];
                    z[g] = s2 + eb4[g];
                }
                int bb = b0 + hf*16 + fb;
                float x0 = x[((size_t)bb*S_ + t)*D_ + 0];
                float x1 = x[((size_t)bb*S_ + t)*D_ + 1];
#pragma unroll
                for (int g = 0; g < 4; g++) z[g] += x0*wi0[g] + x1*wi1[g];
                float cold = hf ? creg1 : creg0;
                float cn = sigm(z[1])*cold + sigm(z[0])*tanh_(z[2]);
                float hn = sigm(z[3])*tanh_(cn);
                if (hf) creg1 = cn; else creg0 = cn;
                stc(&enc_hs[((size_t)bb*S_ + t)*H_ + fhu], hn);
                if (eh16) eh16[((size_t)bb*S_ + t)*H_ + fhu] = __float2half(hn);
            }
            __syncthreads();
        }
        if (t < S_ - 1) gbar32(bar, grp);
    }
    if (tid < 256) {
        stc(&c_fin[(size_t)(b0 + fb)*H_ + fhu],      creg0);
        stc(&c_fin[(size_t)(b0 + 16 + fb)*H_ + fhu], creg1);
    }
}

// ---------------------------------------------------------------------------
// fp32 GEMM, fp16 output (W1e16).
// ---------------------------------------------------------------------------
template<int BM, int BN, int TM, int TN, typename OT>
__global__ __launch_bounds__((BM/TM)*(BN/TN)) void gemm_bias(
    const float* __restrict__ A, const float* __restrict__ Bm,
    const float* __restrict__ bias, OT* __restrict__ C,
    int M, int N, int K)
{
    constexpr int BK = 32;
    constexpr int TH = (BM / TM) * (BN / TN);
    constexpr int AL = BM * BK / TH;
    constexpr int BL = BN * BK / TH;
    constexpr int RP = TH / BK;
    __shared__ float As[BK][BM + 4];
    __shared__ float Bs[BK][BN + 4];
    const int tid = threadIdx.x;
    const int tn = tid % (BN / TN);
    const int tm = tid / (BN / TN);
    const int m0 = blockIdx.x * BM, n0 = blockIdx.y * BN;
    const int lk = tid % BK, lr = tid / BK;

    float acc[TM][TN];
#pragma unroll
    for (int i = 0; i < TM; i++)
#pragma unroll
        for (int j = 0; j < TN; j++) acc[i][j] = 0.f;

    float areg[AL], breg[BL];
#pragma unroll
    for (int i = 0; i < AL; i++) areg[i] = A[(size_t)(m0 + lr + i * RP) * K + lk];
#pragma unroll
    for (int i = 0; i < BL; i++) breg[i] = Bm[(size_t)(n0 + lr + i * RP) * K + lk];

    const int NC = K / BK;
    for (int c = 0; c < NC; c++) {
        __syncthreads();
#pragma unroll
        for (int i = 0; i < AL; i++) As[lk][lr + i * RP] = areg[i];
#pragma unroll
        for (int i = 0; i < BL; i++) Bs[lk][lr + i * RP] = breg[i];
        __syncthreads();
        if (c + 1 < NC) {
            int k0 = (c + 1) * BK;
#pragma unroll
            for (int i = 0; i < AL; i++) areg[i] = A[(size_t)(m0 + lr + i * RP) * K + k0 + lk];
#pragma unroll
            for (int i = 0; i < BL; i++) breg[i] = Bm[(size_t)(n0 + lr + i * RP) * K + k0 + lk];
        }
#pragma unroll
        for (int k = 0; k < BK; k++) {
            float av[TM], bvv[TN];
#pragma unroll
            for (int i = 0; i < TM; i++) av[i] = As[k][tm * TM + i];
#pragma unroll
            for (int j = 0; j < TN; j++) bvv[j] = Bs[k][tn * TN + j];
#pragma unroll
            for (int i = 0; i < TM; i++)
#pragma unroll
                for (int j = 0; j < TN; j++) acc[i][j] += av[i] * bvv[j];
        }
    }
#pragma unroll
    for (int i = 0; i < TM; i++) {
        int m = m0 + tm * TM + i;
#pragma unroll
        for (int j = 0; j < TN; j++) {
            int n = n0 + tn * TN + j;
            C[(size_t)m * N + n] = (OT)(acc[i][j] + bias[n]);
        }
    }
}

// ---------------------------------------------------------------------------
// Persistent decoder, GROUP-LOCAL barriers. Block ab handles attention for
// batch ab with its W1e panel PINNED IN LDS (128KB fp16); LSTM/W2h sliced
// across the 32 blocks of group ab>>5. LDS = 128KB pin + 32KB work = 160KB.
// Glimpse streams eh16 directly (no register prefetch -> no scratch spill);
// eh16 footprint = 4MB/XCD -> L2-resident after the first step.
// ---------------------------------------------------------------------------
__global__ __launch_bounds__(512, 1) void dec_p(
    const float* __restrict__ Wsrc, int packed,
    const float* __restrict__ dxw,
    const float* __restrict__ W2, const float* __restrict__ b2,
    const float* __restrict__ vv, const float* __restrict__ bv,
    const float* __restrict__ enc_hs, const __half* __restrict__ W1e16,
    const __half* __restrict__ eb16, const float* __restrict__ c_fin,
    float* __restrict__ h_dec, float* __restrict__ w2h,
    float* __restrict__ h_glim, float* __restrict__ out,
    unsigned* bar)
{
    extern __shared__ char smem_raw[];
    __half* w1l = (__half*)smem_raw;                   // [128][512] fp16, 128KB
    float* work = (float*)(smem_raw + 131072);         // 8192 floats, 32KB
    float (*Hs)[H_]     = (float (*)[H_])work;
    float (*P)[16][64]  = (float (*)[16][64])work;
    float (*Q)[32][16]  = (float (*)[32][16])work;
    float* qq  = work;
    float* ua  = work + 512;
    float* red = work + 640;
    float* P3  = work + 1024;                          // [8][64][9]

    const int tid = threadIdx.x;
    const int ks = tid >> 6, rw = tid & 63;
    const int ab = blockIdx.x;                         // attention batch
    const int grp = ab >> 5, jt = ab & 31;
    const int b0 = grp * GRP, hu0 = jt * 16;
    const int ln = tid & 63, wv = tid >> 6;

    float w[64];
    load_w64(Wsrc, packed, jt, ks, rw, w);

    const int rsub = (tid >> 4) & 3, jj = tid & 15;
    float w2r[16];
    {
        const float4* p4 = (const float4*)(W2 + (size_t)(hu0 + jj)*H_ + ks*64 + rsub*16);
#pragma unroll
        for (int i = 0; i < 4; i++) {
            float4 t4 = p4[i];
            w2r[4*i]=t4.x; w2r[4*i+1]=t4.y; w2r[4*i+2]=t4.z; w2r[4*i+3]=t4.w;
        }
    }

    const int fb = tid >> 4, fh = tid & 15;
    const int fhu = hu0 + fh;
    float db4[4];
#pragma unroll
    for (int g = 0; g < 4; g++) db4[g] = dxw[g*H_ + fhu];
    const float b2f = b2[fhu];
    float creg0 = c_fin[(size_t)(b0 + (fb & 15))*H_ + fhu];
    float creg1 = c_fin[(size_t)(b0 + 16 + (fb & 15))*H_ + fhu];

    const __half* ebh = eb16 ? (eb16 + (size_t)ab * S_ * H_) : (const __half*)nullptr;
    const float* ebf = enc_hs + (size_t)ab * S_ * H_;
    const float4 vr0 = *(const float4*)(vv + ln*8);
    const float4 vr1 = *(const float4*)(vv + ln*8 + 4);
    const float bvr = bv[0];

    // ---- pin this batch's W1e panel in LDS (plain loads; cross-kernel ok) ----
    {
        const H8* src = (const H8*)(W1e16 + (size_t)ab * S_ * H_);
        H8* dst = (H8*)w1l;
#pragma unroll
        for (int i = 0; i < 16; i++) dst[tid + i * 512] = src[tid + i * 512];
    }
    __syncthreads();

    for (int t = 0; t < S_; t++) {
        // ================ phase L: LSTM ================
        {
            const float* hsrc = (t == 0) ? (enc_hs + (size_t)(S_-1)*H_) : h_glim;
            const size_t hstr = (t == 0) ? (size_t)(S_*H_) : (size_t)H_;
#pragma unroll 1
            for (int hf = 0; hf < 2; hf++) {
                {
                    float r[16];
#pragma unroll
                    for (int i = 0; i < 16; i++)
                        r[i] = ldc(hsrc + (size_t)(b0 + hf*16 + i) * hstr + tid);
#pragma unroll
                    for (int i = 0; i < 16; i++) Hs[i][tid] = r[i];
                }
                __syncthreads();
                float acc[16];
#pragma unroll 2
                for (int b = 0; b < 16; b++) {
                    const float4* hp = (const float4*)&Hs[b][ks * 64];
                    float s = 0.f;
#pragma unroll
                    for (int i = 0; i < 16; i++) {
                        float4 h4 = hp[i];
                        s += h4.x*w[4*i] + h4.y*w[4*i+1] + h4.z*w[4*i+2] + h4.w*w[4*i+3];
                    }
                    acc[b] = s;
                }
                __syncthreads();
#pragma unroll
                for (int b = 0; b < 16; b++) P[ks][b][rw ^ ((b & 3) << 4)] = acc[b];
                __syncthreads();
                if (tid < 256) {
                    float z[4];
#pragma unroll
                    for (int g = 0; g < 4; g++) {
                        int row = g*16 + fh;
                        float s2 = 0.f;
#pragma unroll
                        for (int k8 = 0; k8 < 8; k8++)
                            s2 += P[k8][fb][row ^ ((fb & 3) << 4)];
                        z[g] = s2 + db4[g];
                    }
                    float cold = hf ? creg1 : creg0;
                    float cn = sigm(z[1])*cold + sigm(z[0])*tanh_(z[2]);
                    float hn = sigm(z[3])*tanh_(cn);
                    if (hf) creg1 = cn; else creg0 = cn;
                    stc(&h_dec[(size_t)(b0 + hf*16 + fb)*H_ + fhu], hn);
                }
                __syncthreads();
            }
        }
        gbar32(bar, grp);
        // ================ phase W: w2h ================
        {
            const int kk = ks * 64 + rsub * 16;
#pragma unroll 1
            for (int hf = 0; hf < 2; hf++) {
                {
                    float r[16];
#pragma unroll
                    for (int i = 0; i < 16; i++)
                        r[i] = ldc(h_dec + (size_t)(b0 + hf*16 + i) * H_ + tid);
#pragma unroll
                    for (int i = 0; i < 16; i++) Hs[i][tid] = r[i];
                }
                __syncthreads();
                float a2[16];
#pragma unroll 2
                for (int b = 0; b < 16; b++) {
                    const float4* hp = (const float4*)&Hs[b][kk];
                    float s = 0.f;
#pragma unroll
                    for (int i = 0; i < 4; i++) {
                        float4 h4 = hp[i];
                        s += h4.x*w2r[4*i] + h4.y*w2r[4*i+1] + h4.z*w2r[4*i+2] + h4.w*w2r[4*i+3];
                    }
                    a2[b] = s;
                }
                __syncthreads();
#pragma unroll
                for (int b = 0; b < 16; b++) Q[b][ks*4 + rsub][jj] = a2[b];
                __syncthreads();
                if (tid < 256) {
                    float s2 = 0.f;
#pragma unroll
                    for (int p = 0; p < 32; p++) s2 += Q[fb][p][fh];
                    stc(&w2h[(size_t)(b0 + hf*16 + fb)*H_ + fhu], s2 + b2f);
                }
                __syncthreads();
            }
        }
        gbar32(bar, grp);
        // ================ phase A: attention ================
        {
            qq[tid] = ldc(&w2h[(size_t)ab*H_ + tid]);
            __syncthreads();
            float4 q0 = *(float4*)&qq[ln*8];
            float4 q1 = *(float4*)&qq[ln*8 + 4];
#pragma unroll
            for (int si = 0; si < 16; si++) {
                int s = wv*16 + si;
                H8 w8 = *(const H8*)&w1l[(size_t)s*H_ + ln*8];   // LDS, conflict-free
                float2 a0 = __half22float2(w8.h[0]);
                float2 a1 = __half22float2(w8.h[1]);
                float2 a2 = __half22float2(w8.h[2]);
                float2 a3 = __half22float2(w8.h[3]);
                float sum = tanh_(a0.x+q0.x)*vr0.x + tanh_(a0.y+q0.y)*vr0.y
                          + tanh_(a1.x+q0.z)*vr0.z + tanh_(a1.y+q0.w)*vr0.w
                          + tanh_(a2.x+q1.x)*vr1.x + tanh_(a2.y+q1.y)*vr1.y
                          + tanh_(a3.x+q1.z)*vr1.z + tanh_(a3.y+q1.w)*vr1.w;
#pragma unroll
                for (int off = 32; off; off >>= 1) sum += __shfl_xor(sum, off);
                if (ln == 0) ua[s] = sum + bvr;
            }
            __syncthreads();
            float e = 0.f;
            if (tid < 128) {
                float m = ua[tid];
#pragma unroll
                for (int off = 32; off; off >>= 1) m = fmaxf(m, __shfl_xor(m, off));
                if (ln == 0) red[tid >> 6] = m;
            }
            __syncthreads();
            if (tid < 128) {
                float mx = fmaxf(red[0], red[1]);
                e = __expf(ua[tid] - mx);
                float ss = e;
#pragma unroll
                for (int off = 32; off; off >>= 1) ss += __shfl_xor(ss, off);
                if (ln == 0) red[2 + (tid >> 6)] = ss;
            }
            __syncthreads();
            if (tid < 128) {
                float a = e / (red[2] + red[3]);
                ua[tid] = a;
                out[(size_t)ab*S_*S_ + (size_t)t*S_ + tid] = a;
            }
            __syncthreads();
            // glimpse: stream eh16 (L2-resident), no register prefetch
            float acc8[8];
#pragma unroll
            for (int i = 0; i < 8; i++) acc8[i] = 0.f;
            if (ebh) {
#pragma unroll 4
                for (int si = 0; si < 16; si++) {
                    int s = wv*16 + si;
                    H8 e8 = *(const H8*)(ebh + (size_t)s*H_ + ln*8);
                    float a = ua[s];
                    float2 p0 = __half22float2(e8.h[0]);
                    float2 p1 = __half22float2(e8.h[1]);
                    float2 p2 = __half22float2(e8.h[2]);
                    float2 p3 = __half22float2(e8.h[3]);
                    acc8[0] += a*p0.x; acc8[1] += a*p0.y;
                    acc8[2] += a*p1.x; acc8[3] += a*p1.y;
                    acc8[4] += a*p2.x; acc8[5] += a*p2.y;
                    acc8[6] += a*p3.x; acc8[7] += a*p3.y;
                }
            } else {
#pragma unroll 4
                for (int si = 0; si < 16; si++) {
                    int s = wv*16 + si;
                    const float4* ep = (const float4*)(ebf + (size_t)s*H_ + ln*8);
                    float4 e0 = ep[0], e1 = ep[1];
                    float a = ua[s];
                    acc8[0] += a*e0.x; acc8[1] += a*e0.y;
                    acc8[2] += a*e0.z; acc8[3] += a*e0.w;
                    acc8[4] += a*e1.x; acc8[5] += a*e1.y;
                    acc8[6] += a*e1.z; acc8[7] += a*e1.w;
                }
            }
#pragma unroll
            for (int i = 0; i < 8; i++) P3[wv*576 + ln*9 + i] = acc8[i];
            __syncthreads();
            {
                float g = 0.f;
                int base = (tid >> 3) * 9 + (tid & 7);
#pragma unroll
                for (int w8 = 0; w8 < 8; w8++) g += P3[w8*576 + base];
                stc(&h_glim[(size_t)ab*H_ + tid], g);
            }
        }
        if (t < S_ - 1) gbar32(bar, grp);
    }
}

// ---------------------------------------------------------------------------
extern "C" void kernel_launch(void* const* d_in, const int* in_sizes, int n_in,
                              void* d_out, int out_size, void* d_ws, size_t ws_size,
                              hipStream_t stream)
{
    const float* x    = (const float*)d_in[0];
    const float* eWih = (const float*)d_in[1];
    const float* eWhh = (const float*)d_in[2];
    const float* ebih = (const float*)d_in[3];
    const float* ebhh = (const float*)d_in[4];
    const float* dWih = (const float*)d_in[5];
    const float* dWhh = (const float*)d_in[6];
    const float* dbih = (const float*)d_in[7];
    const float* dbhh = (const float*)d_in[8];
    const float* W1   = (const float*)d_in[9];
    const float* b1   = (const float*)d_in[10];
    const float* W2   = (const float*)d_in[11];
    const float* b2   = (const float*)d_in[12];
    const float* vv   = (const float*)d_in[13];
    const float* bv   = (const float*)d_in[14];
    float* out = (float*)d_out;

    float* ws      = (float*)d_ws;
    float* enc_hs  = ws;                                   // 16777216
    float* h_dec   = enc_hs + (size_t)B_ * S_ * H_;        // 131072
    float* h_glim  = h_dec  + (size_t)B_ * H_;
    float* w2h     = h_glim + (size_t)B_ * H_;
    float* c_fin   = w2h    + (size_t)B_ * H_;
    float* dxw     = c_fin  + (size_t)B_ * H_;             // 2048
    float* ebias   = dxw    + 2048;                        // 2048
    unsigned* bars = (unsigned*)(ebias + 2048);            // 1024 u32
    __half* W1e16  = (__half*)(ebias + 2048 + 1024);       // 8388608 floats
    float* after16 = (float*)(W1e16) + 8388608;
    __half* eh16   = (__half*)after16;                     // optional, 8388608 f
    float* wpk_e   = after16 + 8388608;                    // optional
    float* wpk_d   = wpk_e + 1048576;

    size_t mand_f   = (size_t)(after16 - ws);
    int have_eh16 = (ws_size >= (mand_f + 8388608u) * sizeof(float)) ? 1 : 0;
    int packed    = (ws_size >= (mand_f + 8388608u + 2097152u) * sizeof(float)) ? 1 : 0;
    if (!have_eh16) eh16 = nullptr;

    hipMemsetAsync(bars, 0, 1024 * sizeof(unsigned), stream);
    prep6<<<8, 256, 0, stream>>>(dWih, dbih, dbhh, ebih, ebhh, dxw, ebias);
    if (packed)
        pack_whh<<<8192, 256, 0, stream>>>(eWhh, dWhh, wpk_e, wpk_d);

    const float* We = packed ? wpk_e : eWhh;
    const float* Wd = packed ? wpk_d : dWhh;

    enc_p<<<NBLK, 512, 0, stream>>>(x, eWih, We, packed, ebias, enc_hs, eh16,
                                    c_fin, bars);

    gemm_bias<128, 128, 8, 8, __half>
        <<<dim3((B_ * S_) / 128, H_ / 128), 256, 0, stream>>>(
        enc_hs, W1, b1, W1e16, B_ * S_, H_, H_);

    dec_p<<<NBLK, 512, 163840, stream>>>(Wd, packed, dxw, W2, b2, vv, bv,
                                         enc_hs, W1e16, eh16, c_fin,
                                         h_dec, w2h, h_glim, out, bars + 512);
}